// Round 1
// baseline (320.750 us; speedup 1.0000x reference)
//
#include <hip/hip_runtime.h>
#include <stdint.h>

#define BS 16
#define KQ 8192
#define NTOT (BS + KQ)   // 8208
#define H 768
#define G 5
#define UPD 0.1f
#define QPAD 772         // LDS row stride for staged q (16B-aligned rows, conflict-benign)

// ---- output layout (floats) ----
#define SZ_BN   (BS*NTOT)        // 131328
#define SZ_BNG  (BS*NTOT*G)      // 656640
#define O_GLOGITS 0
#define O_GPROB   (SZ_BNG)
#define O_CTSLOG  (2*SZ_BNG)
#define O_ACC     (O_CTSLOG + SZ_BN)
#define O_NRM     (O_ACC + SZ_BN)
#define O_GLABEL  (O_NRM + G)
#define O_CLABEL  (O_GLABEL + SZ_BN)
#define O_CDIST   (O_CLABEL + SZ_BN)

// ---- workspace layout (float indices) ----
#define W_INV  0                 // G*H   exp(-lg_sigma2)
#define W_MSC  (G*H)             // G*H   mu*inv
#define W_CS   (2*G*H)           // G     C_g = sum mu^2 inv
#define W_SS   (W_CS + G)        // G     S_g = sum lg_sigma2
#define W_LSM  (W_SS + G)        // G     log_softmax(pi)
#define W_P    (W_LSM + G)       // BS*G  sum q^2 inv
#define W_U    (W_P + BS*G)      // BS*G  sum q (mu inv)
#define W_CNT  (W_U + BS*G)      // G
#define W_SUM  (W_CNT + G)       // G
#define W_RMX  (W_SUM + G)       // BS (uint-encoded row max)
#define W_DIAG (W_RMX + BS)      // BS (diagonal sim values)

__device__ __forceinline__ unsigned enc_f(float f) {
    unsigned u = __float_as_uint(f);
    return (u & 0x80000000u) ? ~u : (u | 0x80000000u);
}
__device__ __forceinline__ float dec_f(unsigned k) {
    return (k & 0x80000000u) ? __uint_as_float(k & 0x7fffffffu) : __uint_as_float(~k);
}

__device__ __forceinline__ float wave_red_sum(float v) {
    #pragma unroll
    for (int off = 32; off > 0; off >>= 1) v += __shfl_down(v, off, 64);
    return v;
}

// ---------------- Kernel 1: tiny precompute + zero accumulators ----------------
__global__ __launch_bounds__(256) void prep_kernel(
    const float* __restrict__ sent_q, const float* __restrict__ mu,
    const float* __restrict__ lg, const float* __restrict__ pi,
    float* __restrict__ ws)
{
    const int tid = threadIdx.x;
    for (int i = tid; i < G*H; i += 256) {
        float iv = expf(-lg[i]);
        ws[W_INV + i] = iv;
        ws[W_MSC + i] = mu[i] * iv;
    }
    if (tid < G)  { ws[W_CNT + tid] = 0.f; ws[W_SUM + tid] = 0.f; }
    if (tid < BS) { reinterpret_cast<unsigned*>(ws)[W_RMX + tid] = 0u; }

    const int wave = tid >> 6, lane = tid & 63;
    const int ntasks = 2*G + 2*BS*G;   // 10 + 160
    for (int task = wave; task < ntasks; task += 4) {
        float acc = 0.f;
        if (task < G) {                         // S_g
            int g = task;
            for (int h = lane; h < H; h += 64) acc += lg[g*H + h];
        } else if (task < 2*G) {                // C_g
            int g = task - G;
            for (int h = lane; h < H; h += 64) {
                float m = mu[g*H + h];
                acc += m * m * expf(-lg[g*H + h]);
            }
        } else if (task < 2*G + BS*G) {         // P_bg
            int t2 = task - 2*G; int b = t2 / G, g = t2 % G;
            for (int h = lane; h < H; h += 64) {
                float q = sent_q[b*H + h];
                acc += q * q * expf(-lg[g*H + h]);
            }
        } else {                                // U_bg
            int t2 = task - 2*G - BS*G; int b = t2 / G, g = t2 % G;
            for (int h = lane; h < H; h += 64) {
                float q = sent_q[b*H + h];
                acc += q * mu[g*H + h] * expf(-lg[g*H + h]);
            }
        }
        acc = wave_red_sum(acc);
        if (lane == 0) {
            if (task < G)            ws[W_SS + task] = acc;
            else if (task < 2*G)     ws[W_CS + (task - G)] = acc;
            else if (task < 2*G+BS*G) ws[W_P + (task - 2*G)] = acc;
            else                     ws[W_U + (task - 2*G - BS*G)] = acc;
        }
    }
    if (tid == 0) {
        float mx = pi[0];
        #pragma unroll
        for (int g = 1; g < G; ++g) mx = fmaxf(mx, pi[g]);
        float s = 0.f;
        #pragma unroll
        for (int g = 0; g < G; ++g) s += expf(pi[g] - mx);
        float lse = mx + logf(s);
        #pragma unroll
        for (int g = 0; g < G; ++g) ws[W_LSM + g] = pi[g] - lse;
    }
}

// ---------------- Kernel 2: main per-(b,n) fused compute ----------------
// grid 513 blocks x 256 threads; thread t: b = t>>4, n = blockIdx.x*16 + (t&15)
__global__ __launch_bounds__(256) void main_kernel(
    const float* __restrict__ sent_q,
    const float* __restrict__ sent_k,
    const float* __restrict__ queue,
    const float* __restrict__ rank_mean,
    const float* __restrict__ invp,
    const float* __restrict__ mscp,
    const float* __restrict__ csp,
    const float* __restrict__ ssp,
    const float* __restrict__ lsmp,
    const float* __restrict__ pp,
    const float* __restrict__ up,
    float* cntp, float* sump, unsigned* rmxp, float* diagp,
    float* __restrict__ out)
{
    __shared__ float q_s[BS * QPAD];          // ~48 KB
    __shared__ float sp[2][BS][G][17];        // T/V partials (padded)
    __shared__ float s_T[BS][G];
    __shared__ float s_V[BS][G];
    __shared__ float s_cnt[G], s_sum[G];

    const int t  = threadIdx.x;
    const int b  = t >> 4;
    const int nl = t & 15;
    const int n  = blockIdx.x * BS + nl;

    for (int i = t; i < BS*H; i += 256) {
        q_s[(i / H) * QPAD + (i % H)] = sent_q[i];
    }
    if (t < G) { s_cnt[t] = 0.f; s_sum[t] = 0.f; }
    __syncthreads();

    const float* f = (n < BS) ? (sent_k + n*H) : (queue + (n - BS) * H);

    // main h-loop: sim and R_g = sum_h q f inv_g
    float sim = 0.f;
    float R[G] = {0.f, 0.f, 0.f, 0.f, 0.f};
    const float* qrow = q_s + b * QPAD;
    for (int h = 0; h < H; h += 4) {
        const float4 fv = *reinterpret_cast<const float4*>(f + h);
        const float4 qv = *reinterpret_cast<const float4*>(qrow + h);
        float p0 = qv.x * fv.x;
        float p1 = qv.y * fv.y;
        float p2 = qv.z * fv.z;
        float p3 = qv.w * fv.w;
        sim += (p0 + p1) + (p2 + p3);
        #pragma unroll
        for (int g = 0; g < G; ++g) {
            const float* iv = invp + g*H + h;   // wave-uniform -> scalar loads
            R[g] = fmaf(p3, iv[3], fmaf(p2, iv[2], fmaf(p1, iv[1], fmaf(p0, iv[0], R[g]))));
        }
    }

    // per-n T_ng = sum f^2 inv_g, V_ng = sum f msc_g  (sliced over the 16 b-threads)
    {
        float Tp[G] = {0.f,0.f,0.f,0.f,0.f};
        float Vp[G] = {0.f,0.f,0.f,0.f,0.f};
        for (int s = 0; s < H/BS; ++s) {       // 48 steps
            int h = s * BS + b;
            float fv = f[h];
            float f2 = fv * fv;
            #pragma unroll
            for (int g = 0; g < G; ++g) {
                Tp[g] = fmaf(f2, invp[g*H + h], Tp[g]);
                Vp[g] = fmaf(fv, mscp[g*H + h], Vp[g]);
            }
        }
        #pragma unroll
        for (int g = 0; g < G; ++g) { sp[0][nl][g][b] = Tp[g]; sp[1][nl][g][b] = Vp[g]; }
    }
    __syncthreads();
    if (t < 2*BS*G) {                          // 160 reduce tasks
        int which = t / (BS*G);
        int r = t % (BS*G);
        int rn = r / G, rg = r % G;
        float a = 0.f;
        #pragma unroll
        for (int bb = 0; bb < BS; ++bb) a += sp[which][rn][rg][bb];
        if (which == 0) s_T[rn][rg] = a; else s_V[rn][rg] = a;
    }
    __syncthreads();

    // epilogue per (b, n)
    const float LG2PID = 768.0f * 1.8378770664093453f;
    float lgt[G];
    #pragma unroll
    for (int g = 0; g < G; ++g) {
        float expo = pp[b*G + g] + s_T[nl][g] + csp[g]
                   - 2.f * R[g] - 2.f * up[b*G + g] + 2.f * s_V[nl][g];
        float lp = -0.5f * (LG2PID + ssp[g] + expo);
        lgt[g] = lsmp[g] + lp;
    }
    float mx = lgt[0];
    #pragma unroll
    for (int g = 1; g < G; ++g) mx = fmaxf(mx, lgt[g]);

    const int bn = b * NTOT + n;
    float e[G], se = 0.f;
    #pragma unroll
    for (int g = 0; g < G; ++g) {
        float ln = lgt[g] - mx;
        out[O_GLOGITS + (size_t)bn * G + g] = ln;
        e[g] = expf(ln);
        se += e[g];
    }
    int pred = 0; float bestp = -1.f;
    #pragma unroll
    for (int g = 0; g < G; ++g) {
        float pg = e[g] / se;
        out[O_GPROB + (size_t)bn * G + g] = pg;
        if (pg > bestp) { bestp = pg; pred = g; }   // first max
    }

    // cts_pred: argmin |sim - rank_mean_g| (first min)
    int cp = 0; float bd = fabsf(sim - rank_mean[0]);
    #pragma unroll
    for (int g = 1; g < G; ++g) {
        float d = fabsf(sim - rank_mean[g]);
        if (d < bd) { bd = d; cp = g; }
    }

    float cdist = floorf((sim + 1.0f) * 0.5f * (float)G);

    bool eyev = (n == b);
    bool gold = (n < BS) && (n == ((b + BS/2) & (BS - 1)));

    out[O_GLABEL + bn] = (eyev || gold) ? (float)(G - 1) : (float)cp;
    out[O_CLABEL + bn] = gold ? (float)(G - 1) : (float)pred;
    out[O_ACC    + bn] = eyev ? 0.f : sim;
    out[O_CDIST  + bn] = cdist;
    if (eyev) diagp[b] = sim;

    // counts/sums by unmasked gmm_pred
    atomicAdd(&s_cnt[pred], 1.f);
    atomicAdd(&s_sum[pred], sim);

    // row max over the 16-lane group sharing b
    float m16 = sim;
    #pragma unroll
    for (int off = 8; off > 0; off >>= 1) m16 = fmaxf(m16, __shfl_down(m16, off, 16));
    if (nl == 0) atomicMax(&rmxp[b], enc_f(m16));

    __syncthreads();
    if (t < G) { atomicAdd(&cntp[t], s_cnt[t]); atomicAdd(&sump[t], s_sum[t]); }
}

// ---------------- Kernel 3: cts_logits + new_rank_mean ----------------
__global__ __launch_bounds__(256) void final_kernel(
    const float* __restrict__ rank_mean,
    const float* __restrict__ cntp, const float* __restrict__ sump,
    const unsigned* __restrict__ rmxp, const float* __restrict__ diagp,
    float* __restrict__ out)
{
    int idx = blockIdx.x * 256 + threadIdx.x;   // exactly BS*NTOT
    int b = idx / NTOT;
    int n = idx - b * NTOT;
    float sim = (n == b) ? diagp[b] : out[O_ACC + idx];
    out[O_CTSLOG + idx] = sim - dec_f(rmxp[b]);
    if (idx < G) {
        float c = cntp[idx], s = sump[idx];
        float cur = s / (c + 1e-12f);
        float u = (c != 0.f) ? 1.f : 0.f;
        out[O_NRM + idx] = (1.f - u * UPD) * rank_mean[idx] + u * UPD * cur;
    }
}

extern "C" void kernel_launch(void* const* d_in, const int* in_sizes, int n_in,
                              void* d_out, int out_size, void* d_ws, size_t ws_size,
                              hipStream_t stream) {
    const float* sent_q    = (const float*)d_in[0];
    const float* sent_k    = (const float*)d_in[1];
    const float* queue     = (const float*)d_in[2];
    const float* mu        = (const float*)d_in[3];
    const float* lg        = (const float*)d_in[4];
    const float* pi        = (const float*)d_in[5];
    const float* rank_mean = (const float*)d_in[6];
    float* out = (float*)d_out;
    float* ws  = (float*)d_ws;

    prep_kernel<<<1, 256, 0, stream>>>(sent_q, mu, lg, pi, ws);

    main_kernel<<<NTOT / BS, 256, 0, stream>>>(
        sent_q, sent_k, queue, rank_mean,
        ws + W_INV, ws + W_MSC, ws + W_CS, ws + W_SS, ws + W_LSM,
        ws + W_P, ws + W_U,
        ws + W_CNT, ws + W_SUM,
        reinterpret_cast<unsigned*>(ws + W_RMX), ws + W_DIAG,
        out);

    final_kernel<<<(BS * NTOT) / 256, 256, 0, stream>>>(
        rank_mean, ws + W_CNT, ws + W_SUM,
        reinterpret_cast<const unsigned*>(ws + W_RMX), ws + W_DIAG,
        out);
}

// Round 2
// 157.545 us; speedup vs baseline: 2.0359x; 2.0359x over previous
//
#include <hip/hip_runtime.h>
#include <stdint.h>

#define BS 16
#define KQ 8192
#define NTOT (BS + KQ)   // 8208
#define H 768
#define G 5
#define UPD 0.1f
#define FPAD 772         // LDS row stride (floats) for staged f rows: 772%32==4 -> benign banks

// ---- output layout (floats) ----
#define SZ_BN   (BS*NTOT)        // 131328
#define SZ_BNG  (BS*NTOT*G)      // 656640
#define O_GLOGITS 0
#define O_GPROB   (SZ_BNG)
#define O_CTSLOG  (2*SZ_BNG)
#define O_ACC     (O_CTSLOG + SZ_BN)
#define O_NRM     (O_ACC + SZ_BN)
#define O_GLABEL  (O_NRM + G)
#define O_CLABEL  (O_GLABEL + SZ_BN)
#define O_CDIST   (O_CLABEL + SZ_BN)

// ---- workspace layout (float indices) ----
#define W_INV  0                 // G*H   exp(-lg_sigma2)
#define W_MSC  (G*H)             // G*H   mu*inv
#define W_CS   (2*G*H)           // G     C_g = sum mu^2 inv
#define W_SS   (W_CS + G)        // G     S_g = sum lg_sigma2
#define W_LSM  (W_SS + G)        // G     log_softmax(pi)
#define W_P    (W_LSM + G)       // BS*G  sum q^2 inv
#define W_U    (W_P + BS*G)      // BS*G  sum q (mu inv)
#define W_CNT  (W_U + BS*G)      // G
#define W_SUM  (W_CNT + G)       // G
#define W_RMX  (W_SUM + G)       // BS (uint-encoded row max)
#define W_DIAG (W_RMX + BS)      // BS (diagonal sim values)
#define W_A    (W_DIAG + BS)     // NTOT*G   A_ng = T + 2V + C + S + lg2piD

__device__ __forceinline__ unsigned enc_f(float f) {
    unsigned u = __float_as_uint(f);
    return (u & 0x80000000u) ? ~u : (u | 0x80000000u);
}
__device__ __forceinline__ float dec_f(unsigned k) {
    return (k & 0x80000000u) ? __uint_as_float(k & 0x7fffffffu) : __uint_as_float(~k);
}

__device__ __forceinline__ float wave_red_sum(float v) {
    #pragma unroll
    for (int off = 32; off > 0; off >>= 1) v += __shfl_down(v, off, 64);
    return v;
}

__device__ __forceinline__ void gload_lds16(const float* g, float* l) {
    __builtin_amdgcn_global_load_lds(
        (const __attribute__((address_space(1))) void*)(g),
        (__attribute__((address_space(3))) void*)(l), 16, 0, 0);
}

// ---------------- Kernel 1: parallel precompute + zero accumulators ----------------
// grid 44 x 256. One reduction task per wave (176 waves >= 170 tasks).
__global__ __launch_bounds__(256) void prep_kernel(
    const float* __restrict__ sent_q, const float* __restrict__ mu,
    const float* __restrict__ lg, const float* __restrict__ pi,
    float* __restrict__ ws)
{
    const int tid = threadIdx.x;
    const int gid = blockIdx.x * 256 + tid;
    for (int i = gid; i < G*H; i += gridDim.x * 256) {
        float iv = expf(-lg[i]);
        ws[W_INV + i] = iv;
        ws[W_MSC + i] = mu[i] * iv;
    }
    if (blockIdx.x == 0) {
        if (tid < G)  { ws[W_CNT + tid] = 0.f; ws[W_SUM + tid] = 0.f; }
        if (tid < BS) { reinterpret_cast<unsigned*>(ws)[W_RMX + tid] = 0u; }
        if (tid == 0) {
            float mx = pi[0];
            #pragma unroll
            for (int g = 1; g < G; ++g) mx = fmaxf(mx, pi[g]);
            float s = 0.f;
            #pragma unroll
            for (int g = 0; g < G; ++g) s += expf(pi[g] - mx);
            float lse = mx + logf(s);
            #pragma unroll
            for (int g = 0; g < G; ++g) ws[W_LSM + g] = pi[g] - lse;
        }
    }

    const int lane = tid & 63;
    const int task = blockIdx.x * 4 + (tid >> 6);
    const int ntasks = 2*G + 2*BS*G;   // 170
    if (task < ntasks) {
        float acc = 0.f;
        if (task < G) {                         // S_g
            int g = task;
            for (int h = lane; h < H; h += 64) acc += lg[g*H + h];
        } else if (task < 2*G) {                // C_g
            int g = task - G;
            for (int h = lane; h < H; h += 64) {
                float m = mu[g*H + h];
                acc += m * m * expf(-lg[g*H + h]);
            }
        } else if (task < 2*G + BS*G) {         // P_bg
            int t2 = task - 2*G; int b = t2 / G, g = t2 % G;
            for (int h = lane; h < H; h += 64) {
                float q = sent_q[b*H + h];
                acc += q * q * expf(-lg[g*H + h]);
            }
        } else {                                // U_bg
            int t2 = task - 2*G - BS*G; int b = t2 / G, g = t2 % G;
            for (int h = lane; h < H; h += 64) {
                float q = sent_q[b*H + h];
                acc += q * mu[g*H + h] * expf(-lg[g*H + h]);
            }
        }
        acc = wave_red_sum(acc);
        if (lane == 0) {
            if (task < G)             ws[W_SS + task] = acc;
            else if (task < 2*G)      ws[W_CS + (task - G)] = acc;
            else if (task < 2*G+BS*G) ws[W_P + (task - 2*G)] = acc;
            else                      ws[W_U + (task - 2*G - BS*G)] = acc;
        }
    }
}

// ---------------- Kernel 1b: per-n folded constant A_ng ----------------
// one wave per feature row; grid NTOT/4 x 256
__global__ __launch_bounds__(256) void tv_kernel(
    const float* __restrict__ sent_k, const float* __restrict__ queue,
    const float* __restrict__ invp, const float* __restrict__ mscp,
    const float* __restrict__ csp,  const float* __restrict__ ssp,
    float* __restrict__ A)
{
    const int lane = threadIdx.x & 63;
    const int n = blockIdx.x * 4 + (threadIdx.x >> 6);
    const float* f = (n < BS) ? (sent_k + n*H) : (queue + (n - BS) * H);

    float Tp[G] = {0.f,0.f,0.f,0.f,0.f};
    float Vp[G] = {0.f,0.f,0.f,0.f,0.f};
    #pragma unroll
    for (int j = 0; j < 3; ++j) {
        const int h = j*256 + lane*4;
        const float4 fv = *reinterpret_cast<const float4*>(f + h);
        #pragma unroll
        for (int g = 0; g < G; ++g) {
            const float4 iv = *reinterpret_cast<const float4*>(invp + g*H + h);
            const float4 mv = *reinterpret_cast<const float4*>(mscp + g*H + h);
            Tp[g] = fmaf(fv.x*fv.x, iv.x, Tp[g]);
            Tp[g] = fmaf(fv.y*fv.y, iv.y, Tp[g]);
            Tp[g] = fmaf(fv.z*fv.z, iv.z, Tp[g]);
            Tp[g] = fmaf(fv.w*fv.w, iv.w, Tp[g]);
            Vp[g] = fmaf(fv.x, mv.x, Vp[g]);
            Vp[g] = fmaf(fv.y, mv.y, Vp[g]);
            Vp[g] = fmaf(fv.z, mv.z, Vp[g]);
            Vp[g] = fmaf(fv.w, mv.w, Vp[g]);
        }
    }
    const float LG2PID = 768.0f * 1.8378770664093453f;
    #pragma unroll
    for (int g = 0; g < G; ++g) {
        float T = wave_red_sum(Tp[g]);
        float V = wave_red_sum(Vp[g]);
        if (lane == 0) A[n*G + g] = T + 2.f*V + csp[g] + ssp[g] + LG2PID;
    }
}

// ---------------- Kernel 2: main fused compute ----------------
// grid 513 x 512. t: half = t>>8 (h-split), p = t&255, b = p>>4, nl = p&15.
__global__ __launch_bounds__(512) void main_kernel(
    const float* __restrict__ sent_q,
    const float* __restrict__ sent_k,
    const float* __restrict__ queue,
    const float* __restrict__ rank_mean,
    const float* __restrict__ invp,
    const float* __restrict__ lsmp,
    const float* __restrict__ pp,
    const float* __restrict__ up,
    const float* __restrict__ Ap,
    float* cntp, float* sump, unsigned* rmxp, float* diagp,
    float* __restrict__ out)
{
    __shared__ __align__(16) float fbuf[BS * FPAD];   // 49.4 KB staged f rows
    __shared__ float red[256][8];                      // 8 KB half-combine
    __shared__ float s_cnt[G], s_sum[G];

    const int t    = threadIdx.x;
    const int half = t >> 8;
    const int p    = t & 255;
    const int b    = p >> 4;
    const int nl   = p & 15;
    const int n    = blockIdx.x * BS + nl;
    const int lane = t & 63;
    const int wave = t >> 6;

    if (t < G) { s_cnt[t] = 0.f; s_sum[t] = 0.f; }

    // ---- stage 16 f rows into LDS, coalesced via global_load_lds (wave w: rows 2w,2w+1)
    {
        const int r0 = 2*wave, r1 = 2*wave + 1;
        const int n0 = blockIdx.x * BS + r0, n1 = blockIdx.x * BS + r1;
        const float* s0 = ((n0 < BS) ? (sent_k + n0*H) : (queue + (n0 - BS)*H)) + lane*4;
        const float* s1 = ((n1 < BS) ? (sent_k + n1*H) : (queue + (n1 - BS)*H)) + lane*4;
        #pragma unroll
        for (int k = 0; k < 3; ++k) {
            gload_lds16(s0 + k*256, &fbuf[r0*FPAD + k*256]);
            gload_lds16(s1 + k*256, &fbuf[r1*FPAD + k*256]);
        }
    }
    __syncthreads();   // drains vmcnt before barrier

    // ---- main h-loop over this thread's half (384 floats)
    const int hu = __builtin_amdgcn_readfirstlane(half * 384);  // wave-uniform h base
    const float* qbase = sent_q + b*H + hu;
    const float* fb    = fbuf + nl*FPAD + hu;
    float sim = 0.f;
    float R[G] = {0.f, 0.f, 0.f, 0.f, 0.f};
    #pragma unroll 4
    for (int i = 0; i < 96; ++i) {
        const float4 qv = *reinterpret_cast<const float4*>(qbase + i*4);
        const float4 fv = *reinterpret_cast<const float4*>(fb + i*4);
        float p0 = qv.x * fv.x;
        float p1 = qv.y * fv.y;
        float p2 = qv.z * fv.z;
        float p3 = qv.w * fv.w;
        sim += (p0 + p1) + (p2 + p3);
        #pragma unroll
        for (int g = 0; g < G; ++g) {
            const float* iv = invp + g*H + hu + i*4;   // wave-uniform -> scalar path
            R[g] = fmaf(p3, iv[3], fmaf(p2, iv[2], fmaf(p1, iv[1], fmaf(p0, iv[0], R[g]))));
        }
    }

    // ---- combine halves
    if (half == 1) {
        red[p][0] = sim;
        #pragma unroll
        for (int g = 0; g < G; ++g) red[p][1+g] = R[g];
    }
    __syncthreads();

    if (half == 0) {
        sim += red[p][0];
        #pragma unroll
        for (int g = 0; g < G; ++g) R[g] += red[p][1+g];

        // epilogue per (b, n)
        float lgt[G];
        #pragma unroll
        for (int g = 0; g < G; ++g) {
            float expo = Ap[n*G + g] + pp[b*G + g] - 2.f*up[b*G + g] - 2.f*R[g];
            lgt[g] = lsmp[g] - 0.5f * expo;
        }
        float mx = lgt[0];
        #pragma unroll
        for (int g = 1; g < G; ++g) mx = fmaxf(mx, lgt[g]);

        const int bn = b * NTOT + n;
        float e[G], se = 0.f;
        #pragma unroll
        for (int g = 0; g < G; ++g) {
            float ln = lgt[g] - mx;
            out[O_GLOGITS + (size_t)bn * G + g] = ln;
            e[g] = expf(ln);
            se += e[g];
        }
        int pred = 0; float bestp = -1.f;
        #pragma unroll
        for (int g = 0; g < G; ++g) {
            float pg = e[g] / se;
            out[O_GPROB + (size_t)bn * G + g] = pg;
            if (pg > bestp) { bestp = pg; pred = g; }   // first max
        }

        // cts_pred: argmin |sim - rank_mean_g| (first min)
        int cp = 0; float bd = fabsf(sim - rank_mean[0]);
        #pragma unroll
        for (int g = 1; g < G; ++g) {
            float d = fabsf(sim - rank_mean[g]);
            if (d < bd) { bd = d; cp = g; }
        }

        float cdist = floorf((sim + 1.0f) * 0.5f * (float)G);

        bool eyev = (n == b);
        bool gold = (n < BS) && (n == ((b + BS/2) & (BS - 1)));

        out[O_GLABEL + bn] = (eyev || gold) ? (float)(G - 1) : (float)cp;
        out[O_CLABEL + bn] = gold ? (float)(G - 1) : (float)pred;
        out[O_ACC    + bn] = eyev ? 0.f : sim;
        out[O_CDIST  + bn] = cdist;
        if (eyev) diagp[b] = sim;

        atomicAdd(&s_cnt[pred], 1.f);
        atomicAdd(&s_sum[pred], sim);

        // row max over the 16-lane group sharing b
        float m16 = sim;
        #pragma unroll
        for (int off = 8; off > 0; off >>= 1) m16 = fmaxf(m16, __shfl_down(m16, off, 16));
        if (nl == 0) atomicMax(&rmxp[b], enc_f(m16));
    }
    __syncthreads();
    if (t < G) { atomicAdd(&cntp[t], s_cnt[t]); atomicAdd(&sump[t], s_sum[t]); }
}

// ---------------- Kernel 3: cts_logits + new_rank_mean ----------------
__global__ __launch_bounds__(256) void final_kernel(
    const float* __restrict__ rank_mean,
    const float* __restrict__ cntp, const float* __restrict__ sump,
    const unsigned* __restrict__ rmxp, const float* __restrict__ diagp,
    float* __restrict__ out)
{
    int idx = blockIdx.x * 256 + threadIdx.x;   // exactly BS*NTOT
    int b = idx / NTOT;
    int n = idx - b * NTOT;
    float sim = (n == b) ? diagp[b] : out[O_ACC + idx];
    out[O_CTSLOG + idx] = sim - dec_f(rmxp[b]);
    if (idx < G) {
        float c = cntp[idx], s = sump[idx];
        float cur = s / (c + 1e-12f);
        float u = (c != 0.f) ? 1.f : 0.f;
        out[O_NRM + idx] = (1.f - u * UPD) * rank_mean[idx] + u * UPD * cur;
    }
}

extern "C" void kernel_launch(void* const* d_in, const int* in_sizes, int n_in,
                              void* d_out, int out_size, void* d_ws, size_t ws_size,
                              hipStream_t stream) {
    const float* sent_q    = (const float*)d_in[0];
    const float* sent_k    = (const float*)d_in[1];
    const float* queue     = (const float*)d_in[2];
    const float* mu        = (const float*)d_in[3];
    const float* lg        = (const float*)d_in[4];
    const float* pi        = (const float*)d_in[5];
    const float* rank_mean = (const float*)d_in[6];
    float* out = (float*)d_out;
    float* ws  = (float*)d_ws;

    prep_kernel<<<44, 256, 0, stream>>>(sent_q, mu, lg, pi, ws);

    tv_kernel<<<NTOT/4, 256, 0, stream>>>(
        sent_k, queue, ws + W_INV, ws + W_MSC, ws + W_CS, ws + W_SS, ws + W_A);

    main_kernel<<<NTOT / BS, 512, 0, stream>>>(
        sent_q, sent_k, queue, rank_mean,
        ws + W_INV, ws + W_LSM, ws + W_P, ws + W_U, ws + W_A,
        ws + W_CNT, ws + W_SUM,
        reinterpret_cast<unsigned*>(ws + W_RMX), ws + W_DIAG,
        out);

    final_kernel<<<(BS * NTOT) / 256, 256, 0, stream>>>(
        rank_mean, ws + W_CNT, ws + W_SUM,
        reinterpret_cast<const unsigned*>(ws + W_RMX), ws + W_DIAG,
        out);
}

// Round 3
// 135.881 us; speedup vs baseline: 2.3605x; 1.1594x over previous
//
#include <hip/hip_runtime.h>
#include <stdint.h>

#define BS 16
#define KQ 8192
#define NTOT (BS + KQ)   // 8208
#define H 768
#define G 5
#define UPD 0.1f
#define FPAD 772         // LDS row stride (floats): 772%32==4 -> rotated banks, conflict-free
#define ROWS 4           // f rows per main block
#define LG2PID (768.0f * 1.8378770664093453f)   // common shift, cancels after max-subtract

// ---- output layout (floats) ----
#define SZ_BN   (BS*NTOT)        // 131328
#define SZ_BNG  (BS*NTOT*G)      // 656640
#define O_GLOGITS 0
#define O_GPROB   (SZ_BNG)
#define O_CTSLOG  (2*SZ_BNG)
#define O_ACC     (O_CTSLOG + SZ_BN)
#define O_NRM     (O_ACC + SZ_BN)
#define O_GLABEL  (O_NRM + G)
#define O_CLABEL  (O_GLABEL + SZ_BN)
#define O_CDIST   (O_CLABEL + SZ_BN)

// ---- workspace layout (float indices) ----
#define W_INV   0                    // G*H    exp(-lg_sigma2)
#define W_BB    (G*H)                // BS*G   lsm_g - 0.5(lg2piD + S + C + P - 2U)
#define W_A2    (W_BB + BS*G)        // NTOT*G 0.5*T + V
#define W_CNT8  (W_A2 + NTOT*G)     // 8*16 sharded counts
#define W_SUM8  (W_CNT8 + 128)      // 8*16 sharded sums
#define W_RMX8  (W_SUM8 + 128)      // 8*16 sharded row-max (uint-encoded)
#define W_DIAG  (W_RMX8 + 128)      // BS

__device__ __forceinline__ unsigned enc_f(float f) {
    unsigned u = __float_as_uint(f);
    return (u & 0x80000000u) ? ~u : (u | 0x80000000u);
}
__device__ __forceinline__ float dec_f(unsigned k) {
    return (k & 0x80000000u) ? __uint_as_float(k & 0x7fffffffu) : __uint_as_float(~k);
}

__device__ __forceinline__ float wave_red_sum(float v) {
    #pragma unroll
    for (int off = 32; off > 0; off >>= 1) v += __shfl_down(v, off, 64);
    return v;
}

__device__ __forceinline__ void gload_lds16(const float* g, float* l) {
    __builtin_amdgcn_global_load_lds(
        (const __attribute__((address_space(1))) void*)(g),
        (__attribute__((address_space(3))) void*)(l), 16, 0, 0);
}

// ---------------- Kernel 1: fused tv (A2_ng) + prep (BB_bg, inv, zeros) ----------------
// grid 2052 x 256; wave w of block bx owns feature row n = bx*4 + w.
__global__ __launch_bounds__(256) void k1_kernel(
    const float* __restrict__ sent_q, const float* __restrict__ sent_k,
    const float* __restrict__ queue,  const float* __restrict__ mu,
    const float* __restrict__ lg,     const float* __restrict__ pi,
    float* __restrict__ ws)
{
    const int t = threadIdx.x;
    const int lane = t & 63;
    const int w = t >> 6;
    const int bx = blockIdx.x;

    // ---- tv part: A2_ng = 0.5*sum f^2 inv + sum f mu inv  (inv computed on the fly)
    {
        const int n = bx * ROWS + w;
        const float* f = (n < BS) ? (sent_k + n*H) : (queue + (n - BS) * H);
        float Tp[G] = {0.f,0.f,0.f,0.f,0.f};
        float Vp[G] = {0.f,0.f,0.f,0.f,0.f};
        #pragma unroll
        for (int j = 0; j < 3; ++j) {
            const int h = j*256 + lane*4;
            const float4 fv = *reinterpret_cast<const float4*>(f + h);
            const float fx2 = fv.x*fv.x, fy2 = fv.y*fv.y, fz2 = fv.z*fv.z, fw2 = fv.w*fv.w;
            #pragma unroll
            for (int g = 0; g < G; ++g) {
                const float4 lv = *reinterpret_cast<const float4*>(lg + g*H + h);
                const float4 mv = *reinterpret_cast<const float4*>(mu + g*H + h);
                float ix = expf(-lv.x), iy = expf(-lv.y), iz = expf(-lv.z), iw = expf(-lv.w);
                Tp[g] = fmaf(fx2, ix, Tp[g]);
                Tp[g] = fmaf(fy2, iy, Tp[g]);
                Tp[g] = fmaf(fz2, iz, Tp[g]);
                Tp[g] = fmaf(fw2, iw, Tp[g]);
                Vp[g] = fmaf(fv.x, mv.x*ix, Vp[g]);
                Vp[g] = fmaf(fv.y, mv.y*iy, Vp[g]);
                Vp[g] = fmaf(fv.z, mv.z*iz, Vp[g]);
                Vp[g] = fmaf(fv.w, mv.w*iw, Vp[g]);
            }
        }
        #pragma unroll
        for (int g = 0; g < G; ++g) {
            float T = wave_red_sum(Tp[g]);
            float V = wave_red_sum(Vp[g]);
            if (lane == 0) ws[W_A2 + n*G + g] = 0.5f*T + V;
        }
    }

    // ---- prep duties
    if (bx < BS*G) {                     // 80 blocks: wave 0 computes BB_bg
        if (w == 0) {
            const int b = bx / G, g = bx % G;
            float accP = 0.f, accU = 0.f, accC = 0.f, accS = 0.f;
            for (int h = lane; h < H; h += 64) {
                float qv  = sent_q[b*H + h];
                float lgv = lg[g*H + h];
                float m   = mu[g*H + h];
                float iv  = expf(-lgv);
                accP = fmaf(qv*qv, iv, accP);
                accU = fmaf(qv*m,  iv, accU);
                accC = fmaf(m*m,   iv, accC);
                accS += lgv;
            }
            accP = wave_red_sum(accP);
            accU = wave_red_sum(accU);
            accC = wave_red_sum(accC);
            accS = wave_red_sum(accS);
            if (lane == 0) {
                float mx = pi[0];
                #pragma unroll
                for (int gg = 1; gg < G; ++gg) mx = fmaxf(mx, pi[gg]);
                float s = 0.f;
                #pragma unroll
                for (int gg = 0; gg < G; ++gg) s += expf(pi[gg] - mx);
                float lse = mx + logf(s);
                ws[W_BB + b*G + g] =
                    (pi[g] - lse) - 0.5f*(LG2PID + accS + accC + accP - 2.f*accU);
            }
        }
    } else if (bx < BS*G + 15) {         // 15 blocks: write inv (G*H = 3840 = 15*256)
        const int i = (bx - BS*G) * 256 + t;
        ws[W_INV + i] = expf(-lg[i]);
    } else if (bx == BS*G + 15) {        // zero sharded accumulators (384 floats)
        for (int i = t; i < 384; i += 256) ws[W_CNT8 + i] = 0.f;
    }
}

// ---------------- Kernel 2: main fused compute ----------------
// grid 2052 x 256. wave w = h-quarter; lane p: b = p>>2, nl = p&3, n = bx*4 + nl.
__global__ __launch_bounds__(256, 8) void main_kernel(
    const float* __restrict__ sent_q,
    const float* __restrict__ sent_k,
    const float* __restrict__ queue,
    const float* __restrict__ rank_mean,
    const float* __restrict__ invp,
    const float* __restrict__ BBp,
    const float* __restrict__ A2p,
    float* cnt8, float* sum8, unsigned* rmx8, float* diagp,
    float* __restrict__ out)
{
    __shared__ __align__(16) float fbuf[ROWS * FPAD];   // 12.3 KB
    __shared__ float red[64][21];                        // 5.25 KB, stride 21: conflict-free
    __shared__ float s_BB[BS*G];
    __shared__ float s_A2[ROWS*G];
    __shared__ float s_cnt[G], s_sum[G];

    const int t    = threadIdx.x;
    const int lane = t & 63;
    const int w    = t >> 6;            // h-quarter (wave-uniform)
    const int b    = lane >> 2;
    const int nl   = lane & 3;
    const int bx   = blockIdx.x;
    const int n    = bx * ROWS + nl;

    if (t < BS*G) s_BB[t] = BBp[t];
    if (t >= 128 && t < 128 + ROWS*G) s_A2[t-128] = A2p[bx*ROWS*G + (t-128)];
    if (t >= 160 && t < 160 + G) { s_cnt[t-160] = 0.f; s_sum[t-160] = 0.f; }

    // stage 4 f rows: wave w stages row w (coalesced, LDS dest = base + lane*16B)
    {
        const int rn = bx * ROWS + w;
        const float* src = ((rn < BS) ? (sent_k + rn*H) : (queue + (rn - BS)*H)) + lane*4;
        #pragma unroll
        for (int k = 0; k < 3; ++k)
            gload_lds16(src + k*256, &fbuf[w*FPAD + k*256]);
    }
    __syncthreads();

    // main h-loop over this wave's quarter (192 floats)
    const int hu = __builtin_amdgcn_readfirstlane(w * 192);
    const float* qb = sent_q + b*H + hu;
    const float* fb = fbuf + nl*FPAD + hu;
    float sim = 0.f;
    float R[G] = {0.f, 0.f, 0.f, 0.f, 0.f};
    #pragma unroll 4
    for (int i = 0; i < 48; ++i) {
        const float4 qv = *reinterpret_cast<const float4*>(qb + i*4);
        const float4 fv = *reinterpret_cast<const float4*>(fb + i*4);
        float p0 = qv.x * fv.x;
        float p1 = qv.y * fv.y;
        float p2 = qv.z * fv.z;
        float p3 = qv.w * fv.w;
        sim += (p0 + p1) + (p2 + p3);
        #pragma unroll
        for (int g = 0; g < G; ++g) {
            const float* iv = invp + g*H + hu + i*4;   // wave-uniform -> scalar loads
            R[g] = fmaf(p3, iv[3], fmaf(p2, iv[2], fmaf(p1, iv[1], fmaf(p0, iv[0], R[g]))));
        }
    }

    // combine quarters
    if (w) {
        red[lane][(w-1)*6 + 0] = sim;
        #pragma unroll
        for (int g = 0; g < G; ++g) red[lane][(w-1)*6 + 1 + g] = R[g];
    }
    __syncthreads();

    if (w == 0) {
        #pragma unroll
        for (int qq = 0; qq < 3; ++qq) {
            sim += red[lane][qq*6];
            #pragma unroll
            for (int g = 0; g < G; ++g) R[g] += red[lane][qq*6 + 1 + g];
        }

        float lgt[G];
        #pragma unroll
        for (int g = 0; g < G; ++g)
            lgt[g] = s_BB[b*G + g] - s_A2[nl*G + g] + R[g];
        float mx = lgt[0];
        #pragma unroll
        for (int g = 1; g < G; ++g) mx = fmaxf(mx, lgt[g]);

        const int bn = b * NTOT + n;
        float e[G], se = 0.f;
        #pragma unroll
        for (int g = 0; g < G; ++g) {
            float ln = lgt[g] - mx;
            out[O_GLOGITS + (size_t)bn * G + g] = ln;
            e[g] = expf(ln);
            se += e[g];
        }
        int pred = 0; float bestp = -1.f;
        #pragma unroll
        for (int g = 0; g < G; ++g) {
            float pg = e[g] / se;
            out[O_GPROB + (size_t)bn * G + g] = pg;
            if (pg > bestp) { bestp = pg; pred = g; }   // first max
        }

        int cp = 0; float bd = fabsf(sim - rank_mean[0]);
        #pragma unroll
        for (int g = 1; g < G; ++g) {
            float d = fabsf(sim - rank_mean[g]);
            if (d < bd) { bd = d; cp = g; }             // first min
        }

        float cdist = floorf((sim + 1.0f) * 0.5f * (float)G);

        bool eyev = (n == b);
        bool gold = (n < BS) && (n == ((b + BS/2) & (BS - 1)));

        out[O_GLABEL + bn] = (eyev || gold) ? (float)(G - 1) : (float)cp;
        out[O_CLABEL + bn] = gold ? (float)(G - 1) : (float)pred;
        out[O_ACC    + bn] = eyev ? 0.f : sim;
        out[O_CDIST  + bn] = cdist;
        if (eyev) diagp[b] = sim;

        atomicAdd(&s_cnt[pred], 1.f);
        atomicAdd(&s_sum[pred], sim);

        // row max over the 4 nl lanes sharing b, then sharded global max
        float m4 = sim;
        m4 = fmaxf(m4, __shfl_down(m4, 2, 4));
        m4 = fmaxf(m4, __shfl_down(m4, 1, 4));
        if (nl == 0) atomicMax(&rmx8[(bx & 7) * 16 + b], enc_f(m4));
    }
    __syncthreads();
    if (t < G) {
        atomicAdd(&cnt8[(bx & 7) * 16 + t], s_cnt[t]);
        atomicAdd(&sum8[(bx & 7) * 16 + t], s_sum[t]);
    }
}

// ---------------- Kernel 3: cts_logits (float4) + new_rank_mean ----------------
__global__ __launch_bounds__(256) void final_kernel(
    const float* __restrict__ rank_mean,
    const float* __restrict__ cnt8, const float* __restrict__ sum8,
    const unsigned* __restrict__ rmx8, const float* __restrict__ diagp,
    float* __restrict__ out)
{
    const int i4 = blockIdx.x * 256 + threadIdx.x;
    if (i4 < G) {
        float c = 0.f, s = 0.f;
        #pragma unroll
        for (int j = 0; j < 8; ++j) { c += cnt8[j*16 + i4]; s += sum8[j*16 + i4]; }
        float cur = s / (c + 1e-12f);
        float u = (c != 0.f) ? 1.f : 0.f;
        out[O_NRM + i4] = (1.f - u * UPD) * rank_mean[i4] + u * UPD * cur;
    }
    if (i4 >= SZ_BN/4) return;
    const int i0 = i4 * 4;
    const int b  = i0 / NTOT;          // NTOT%4==0 -> all 4 share b
    const int n0 = i0 - b * NTOT;
    unsigned mk = 0u;
    #pragma unroll
    for (int j = 0; j < 8; ++j) mk = max(mk, rmx8[j*16 + b]);
    const float rm = dec_f(mk);
    float4 v = *reinterpret_cast<const float4*>(&out[O_ACC + i0]);
    if (b >= n0 && b < n0 + 4) {
        float d = diagp[b];
        int r = b - n0;
        if (r == 0) v.x = d; else if (r == 1) v.y = d;
        else if (r == 2) v.z = d; else v.w = d;
    }
    float4 o;
    o.x = v.x - rm; o.y = v.y - rm; o.z = v.z - rm; o.w = v.w - rm;
    *reinterpret_cast<float4*>(&out[O_CTSLOG + i0]) = o;
}

extern "C" void kernel_launch(void* const* d_in, const int* in_sizes, int n_in,
                              void* d_out, int out_size, void* d_ws, size_t ws_size,
                              hipStream_t stream) {
    const float* sent_q    = (const float*)d_in[0];
    const float* sent_k    = (const float*)d_in[1];
    const float* queue     = (const float*)d_in[2];
    const float* mu        = (const float*)d_in[3];
    const float* lg        = (const float*)d_in[4];
    const float* pi        = (const float*)d_in[5];
    const float* rank_mean = (const float*)d_in[6];
    float* out = (float*)d_out;
    float* ws  = (float*)d_ws;

    k1_kernel<<<NTOT / ROWS, 256, 0, stream>>>(
        sent_q, sent_k, queue, mu, lg, pi, ws);

    main_kernel<<<NTOT / ROWS, 256, 0, stream>>>(
        sent_q, sent_k, queue, rank_mean,
        ws + W_INV, ws + W_BB, ws + W_A2,
        ws + W_CNT8, ws + W_SUM8,
        reinterpret_cast<unsigned*>(ws + W_RMX8), ws + W_DIAG,
        out);

    final_kernel<<<(SZ_BN/4 + 255) / 256, 256, 0, stream>>>(
        rank_mean, ws + W_CNT8, ws + W_SUM8,
        reinterpret_cast<const unsigned*>(ws + W_RMX8), ws + W_DIAG,
        out);
}